// Round 1
// baseline (140.940 us; speedup 1.0000x reference)
//
#include <hip/hip_runtime.h>
#include <hip/hip_bf16.h>

typedef __bf16 bf16_t;
typedef __bf16 bf16x8 __attribute__((ext_vector_type(8)));
typedef __bf16 bf16x4 __attribute__((ext_vector_type(4)));
typedef float f32x4 __attribute__((ext_vector_type(4)));

#define FDIM 512
#define BM 64

// Kernel 1: Qt[g][f] = bf16(Q[f][g])  (transpose + convert, 512x512)
__global__ void qtrans_kernel(const float* __restrict__ Q, bf16_t* __restrict__ Qt) {
    int idx = blockIdx.x * 256 + threadIdx.x;   // idx = g*512 + f
    int g = idx >> 9;
    int f = idx & 511;
    Qt[idx] = (bf16_t)Q[f * FDIM + g];
}

// Kernel 2: fused  out[b] = sum_g (x Q)[b,g] * x[b,g]
// 256 threads = 4 waves. BM=64 rows/block. Waves split N into col-pairs of 32.
// Triangular skip: col-pair p (cols 32p..32p+31) needs K-steps 0..p (K=32 each).
__global__ __launch_bounds__(256, 2) void bilinear_kernel(
    const float* __restrict__ x, const bf16_t* __restrict__ Qt,
    float* __restrict__ out)
{
    __shared__ bf16_t xs[BM * FDIM];   // 64 KB, XOR-swizzled: elem ^= (row&7)<<3
    __shared__ float rsum[4][BM];      // per-wave row partials

    const int tid = threadIdx.x;
    const size_t blk = (size_t)blockIdx.x * BM;
    const float4* xin = (const float4*)(x + blk * FDIM);

    // ---- stage x block: fp32 -> bf16, swizzled LDS ----
#pragma unroll
    for (int it = 0; it < 32; ++it) {
        int i4 = it * 256 + tid;          // float4 index within block
        float4 v = xin[i4];
        int e = i4 * 4;                   // element offset (multiple of 4)
        int row = e >> 9;
        int se = e ^ ((row & 7) << 3);    // 8B-chunk-preserving swizzle
        bf16x4 b;
        b[0] = (bf16_t)v.x; b[1] = (bf16_t)v.y; b[2] = (bf16_t)v.z; b[3] = (bf16_t)v.w;
        *(bf16x4*)(xs + se) = b;
    }
    __syncthreads();

    const int w   = tid >> 6;
    const int l   = tid & 63;
    const int col = l & 15;   // A-frag row / B-frag col / D col
    const int kg  = l >> 4;   // k-group

    float rs[4][4];
#pragma unroll
    for (int m = 0; m < 4; ++m)
#pragma unroll
        for (int j = 0; j < 4; ++j) rs[m][j] = 0.0f;

    // balanced pair assignment: each wave's K-step total = 34
    const int pr[4] = {w, w + 4, 11 - w, 15 - w};

#pragma unroll
    for (int pi = 0; pi < 4; ++pi) {
        const int p  = pr[pi];
        const int c0 = p * 32;
        const int nk = p + 1;

        f32x4 acc[2][4];
#pragma unroll
        for (int n = 0; n < 2; ++n)
#pragma unroll
            for (int m = 0; m < 4; ++m)
#pragma unroll
                for (int j = 0; j < 4; ++j) acc[n][m][j] = 0.0f;

        // B-frag base: Qt[(c0+col)][kg*8 + ks*32 ...], contiguous 16B per lane
        const bf16_t* qb0 = Qt + (size_t)(c0 + col) * FDIM + kg * 8;
        const bf16_t* qb1 = qb0 + 16 * FDIM;
        bf16x8 b0 = *(const bf16x8*)(qb0);
        bf16x8 b1 = *(const bf16x8*)(qb1);

        for (int ks = 0; ks < nk; ++ks) {
            bf16x8 nb0 = b0, nb1 = b1;
            if (ks + 1 < nk) {                       // prefetch next K-step
                nb0 = *(const bf16x8*)(qb0 + (ks + 1) * 32);
                nb1 = *(const bf16x8*)(qb1 + (ks + 1) * 32);
            }
            bf16x8 a[4];
#pragma unroll
            for (int m = 0; m < 4; ++m) {
                int r = m * 16 + col;
                int e = (r * FDIM + ks * 32 + kg * 8) ^ ((r & 7) << 3);
                a[m] = *(const bf16x8*)(xs + e);
            }
#pragma unroll
            for (int m = 0; m < 4; ++m) {
                acc[0][m] = __builtin_amdgcn_mfma_f32_16x16x32_bf16(a[m], b0, acc[0][m], 0, 0, 0);
                acc[1][m] = __builtin_amdgcn_mfma_f32_16x16x32_bf16(a[m], b1, acc[1][m], 0, 0, 0);
            }
            b0 = nb0; b1 = nb1;
        }

        // epilogue: rs += xQ_frag * x  (D layout: col = lane&15, row = kg*4 + j)
#pragma unroll
        for (int m = 0; m < 4; ++m) {
#pragma unroll
            for (int j = 0; j < 4; ++j) {
                int r  = m * 16 + kg * 4 + j;
                int e0 = (r * FDIM + c0 + col)      ^ ((r & 7) << 3);
                int e1 = (r * FDIM + c0 + 16 + col) ^ ((r & 7) << 3);
                rs[m][j] += acc[0][m][j] * (float)xs[e0]
                          + acc[1][m][j] * (float)xs[e1];
            }
        }
    }

    // ---- reduce: 16 lanes (same kg) hold different cols of the same rows ----
#pragma unroll
    for (int m = 0; m < 4; ++m) {
#pragma unroll
        for (int j = 0; j < 4; ++j) {
            float v = rs[m][j];
            v += __shfl_xor(v, 1);
            v += __shfl_xor(v, 2);
            v += __shfl_xor(v, 4);
            v += __shfl_xor(v, 8);
            rs[m][j] = v;
        }
    }
    if (col == 0) {
#pragma unroll
        for (int m = 0; m < 4; ++m)
#pragma unroll
            for (int j = 0; j < 4; ++j)
                rsum[w][m * 16 + kg * 4 + j] = rs[m][j];
    }
    __syncthreads();

    if (tid < BM) {
        out[blk + tid] = rsum[0][tid] + rsum[1][tid] + rsum[2][tid] + rsum[3][tid];
    }
}

extern "C" void kernel_launch(void* const* d_in, const int* in_sizes, int n_in,
                              void* d_out, int out_size, void* d_ws, size_t ws_size,
                              hipStream_t stream) {
    const float* x = (const float*)d_in[0];
    const float* Q = (const float*)d_in[1];
    float* out = (float*)d_out;
    bf16_t* Qt = (bf16_t*)d_ws;        // needs 512*512*2 = 512 KB scratch

    const int B = in_sizes[0] / FDIM;  // 131072

    qtrans_kernel<<<(FDIM * FDIM) / 256, 256, 0, stream>>>(Q, Qt);
    bilinear_kernel<<<B / BM, 256, 0, stream>>>(x, Qt, out);
}